// Round 2
// baseline (105.017 us; speedup 1.0000x reference)
//
#include <hip/hip_runtime.h>

#define SDIM 4096
#define DDIM 64
#define HN   16
#define BH   64
#define NC   8

// ---------------------------------------------------------------------------
// k1: per (bh, chunk) compute partial KV[64][64] = sum_s K[s][d]*V[s][e]
//     (K gets relu + mask) and partial ksum[64].
//     Partials are written into d_out (used as scratch; k3 overwrites all of
//     d_out later, stream order makes this safe and deterministic).
// ---------------------------------------------------------------------------
__global__ __launch_bounds__(256) void k1_kv(
    const float* __restrict__ K, const float* __restrict__ V,
    const int* __restrict__ mask,
    float* __restrict__ KVp, float* __restrict__ ksump)
{
    __shared__ float lds[16384];           // 64 KB: Ks[128][64] | Vs[128][64]
    float* Ks = lds;
    float* Vs = lds + 8192;

    const int bh = blockIdx.x / NC;
    const int ch = blockIdx.x % NC;
    const int b  = bh / HN;
    const int tid  = threadIdx.x;
    const int wave = tid >> 6;
    const int lane = tid & 63;
    const int di = lane >> 3;              // 0..7 (d sub-block)
    const int ej = lane & 7;               // 0..7 (e sub-block)
    const long base = (long)bh * SDIM * DDIM;
    const int s0 = ch * (SDIM / NC);       // 512 rows per block

    float acc[8][8];
#pragma unroll
    for (int i = 0; i < 8; ++i)
#pragma unroll
        for (int j = 0; j < 8; ++j) acc[i][j] = 0.f;
    float ksacc[8];
#pragma unroll
    for (int i = 0; i < 8; ++i) ksacc[i] = 0.f;

    for (int it = 0; it < (SDIM / NC) / 128; ++it) {   // 4 iters of 128 rows
        const int r0 = s0 + it * 128;
        __syncthreads();
        // stage 128x64 of K (relu+mask) and V, coalesced float4
#pragma unroll
        for (int i = 0; i < 8; ++i) {
            const int f  = tid + i * 256;      // float4 index 0..2047
            const int r  = f >> 4;             // row 0..127
            const int c4 = (f & 15) << 2;      // col 0..60
            const int sg = r0 + r;
            float4 kq = *(const float4*)(K + base + (long)sg * DDIM + c4);
            const float mv = mask[b * SDIM + sg] ? 1.f : 0.f;
            kq.x = fmaxf(kq.x, 0.f) * mv;
            kq.y = fmaxf(kq.y, 0.f) * mv;
            kq.z = fmaxf(kq.z, 0.f) * mv;
            kq.w = fmaxf(kq.w, 0.f) * mv;
            *(float4*)(Ks + r * 64 + c4) = kq;
            *(float4*)(Vs + r * 64 + c4) =
                *(const float4*)(V + base + (long)sg * DDIM + c4);
        }
        __syncthreads();
        const int rb = wave * 32;              // each wave owns 32 rows
#pragma unroll 2
        for (int s = 0; s < 32; ++s) {
            float kf[8], vf[8];
            *(float4*)(kf)     = *(const float4*)(Ks + (rb + s) * 64 + di * 8);
            *(float4*)(kf + 4) = *(const float4*)(Ks + (rb + s) * 64 + di * 8 + 4);
            *(float4*)(vf)     = *(const float4*)(Vs + (rb + s) * 64 + ej * 8);
            *(float4*)(vf + 4) = *(const float4*)(Vs + (rb + s) * 64 + ej * 8 + 4);
#pragma unroll
            for (int i = 0; i < 8; ++i)
#pragma unroll
                for (int j = 0; j < 8; ++j)
                    acc[i][j] = fmaf(kf[i], vf[j], acc[i][j]);
            if (ej == 0) {
#pragma unroll
                for (int i = 0; i < 8; ++i) ksacc[i] += kf[i];
            }
        }
    }
    // cross-wave reduce of KV in LDS (reuse staging space: 4 x 4096 floats)
    __syncthreads();
#pragma unroll
    for (int i = 0; i < 8; ++i)
#pragma unroll
        for (int j = 0; j < 8; ++j)
            lds[wave * 4096 + (di * 8 + i) * 64 + ej * 8 + j] = acc[i][j];
    __syncthreads();
    float* outp = KVp + ((long)bh * NC + ch) * 4096;
    for (int i = 0; i < 16; ++i) {
        const int idx = i * 256 + tid;         // conflict-free, coalesced
        outp[idx] = lds[idx] + lds[4096 + idx] + lds[8192 + idx] + lds[12288 + idx];
    }
    // ksum cross-wave reduce
    __syncthreads();
    if (ej == 0) {
#pragma unroll
        for (int i = 0; i < 8; ++i) lds[wave * 64 + di * 8 + i] = ksacc[i];
    }
    __syncthreads();
    if (tid < 64) {
        ksump[((long)bh * NC + ch) * 64 + tid] =
            lds[tid] + lds[64 + tid] + lds[128 + tid] + lds[192 + tid];
    }
}

// ---------------------------------------------------------------------------
// k2: reduce NC chunk partials (in d_out scratch) -> final KV[bh][64][64],
//     ksum[bh][64] (in d_ws, 1.07 MB total).
// ---------------------------------------------------------------------------
__global__ __launch_bounds__(256) void k2_reduce(
    const float* __restrict__ KVp, const float* __restrict__ ksump,
    float* __restrict__ KV, float* __restrict__ ksum)
{
    const int bh = blockIdx.x;
    const int tid = threadIdx.x;
#pragma unroll
    for (int i = 0; i < 16; ++i) {
        const int idx = i * 256 + tid;
        float v = 0.f;
#pragma unroll
        for (int c = 0; c < NC; ++c) v += KVp[((long)bh * NC + c) * 4096 + idx];
        KV[(long)bh * 4096 + idx] = v;
    }
    if (tid < 64) {
        float v = 0.f;
#pragma unroll
        for (int c = 0; c < NC; ++c) v += ksump[((long)bh * NC + c) * 64 + tid];
        ksum[bh * 64 + tid] = v;
    }
}

// ---------------------------------------------------------------------------
// k3: out[s][e] = (relu(Q[s]) . KV[:,e]) / (relu(Q[s]) . ksum)
//     128 threads = 2 waves; each wave computes a 64x64 output tile via
//     per-lane 8x8 outer products. Q staged transposed ([d][s], pad 65).
//     Overwrites ALL of d_out (including the k1 partial scratch region).
// ---------------------------------------------------------------------------
__global__ __launch_bounds__(128) void k3_out(
    const float* __restrict__ Q, const float* __restrict__ KV,
    const float* __restrict__ ksum, float* __restrict__ out)
{
    __shared__ float kvs[4096];            // 16 KB
    __shared__ float kss[64];
    __shared__ float qt[2][64 * 65];       // 33.3 KB, transposed Q tiles

    const int bh    = blockIdx.x >> 5;     // 32 strips of 128 rows
    const int strip = blockIdx.x & 31;
    const int tid  = threadIdx.x;
    const int wave = tid >> 6;
    const int lane = tid & 63;
    const int si = lane >> 3;              // 0..7 (s sub-block)
    const int ej = lane & 7;               // 0..7 (e sub-block)

    for (int i = tid; i < 1024; i += 128)
        *(float4*)(kvs + i * 4) = *(const float4*)(KV + (long)bh * 4096 + i * 4);
    if (tid < 64) kss[tid] = ksum[bh * 64 + tid];

    const int srow0 = strip * 128 + wave * 64;
    const float* qp = Q + ((long)bh * SDIM + srow0) * DDIM;
    float* qtw = &qt[wave][0];
#pragma unroll
    for (int i = 0; i < 16; ++i) {
        const int f  = lane + i * 64;      // float4 index 0..1023
        const int r  = f >> 4;             // row 0..63
        const int c4 = (f & 15) << 2;      // col
        float4 q = *(const float4*)(qp + r * 64 + c4);
        q.x = fmaxf(q.x, 0.f); q.y = fmaxf(q.y, 0.f);
        q.z = fmaxf(q.z, 0.f); q.w = fmaxf(q.w, 0.f);
        qtw[(c4 + 0) * 65 + r] = q.x;      // transposed store, 2-way (free)
        qtw[(c4 + 1) * 65 + r] = q.y;
        qtw[(c4 + 2) * 65 + r] = q.z;
        qtw[(c4 + 3) * 65 + r] = q.w;
    }
    __syncthreads();

    float acc[8][8];
#pragma unroll
    for (int i = 0; i < 8; ++i)
#pragma unroll
        for (int j = 0; j < 8; ++j) acc[i][j] = 0.f;
    float nacc[8];
#pragma unroll
    for (int i = 0; i < 8; ++i) nacc[i] = 0.f;

#pragma unroll 4
    for (int d = 0; d < 64; ++d) {
        float qv[8];
#pragma unroll
        for (int r = 0; r < 8; ++r) qv[r] = qtw[d * 65 + si * 8 + r];
        float kvv[8];
        *(float4*)(kvv)     = *(const float4*)(kvs + d * 64 + ej * 8);
        *(float4*)(kvv + 4) = *(const float4*)(kvs + d * 64 + ej * 8 + 4);
        const float ksd = kss[d];
#pragma unroll
        for (int i = 0; i < 8; ++i)
#pragma unroll
            for (int j = 0; j < 8; ++j)
                acc[i][j] = fmaf(qv[i], kvv[j], acc[i][j]);
        if (ej == 0) {
#pragma unroll
            for (int i = 0; i < 8; ++i) nacc[i] = fmaf(qv[i], ksd, nacc[i]);
        }
    }

#pragma unroll
    for (int r = 0; r < 8; ++r) {
        const float nrm = __shfl(nacc[r], lane & 56);   // from ej==0 lane of group
        const float inv = 1.0f / nrm;
        float4 o0, o1;
        o0.x = acc[r][0] * inv; o0.y = acc[r][1] * inv;
        o0.z = acc[r][2] * inv; o0.w = acc[r][3] * inv;
        o1.x = acc[r][4] * inv; o1.y = acc[r][5] * inv;
        o1.z = acc[r][6] * inv; o1.w = acc[r][7] * inv;
        float* op = out + ((long)bh * SDIM + srow0 + si * 8 + r) * DDIM + ej * 8;
        *(float4*)op       = o0;
        *(float4*)(op + 4) = o1;
    }
}

extern "C" void kernel_launch(void* const* d_in, const int* in_sizes, int n_in,
                              void* d_out, int out_size, void* d_ws, size_t ws_size,
                              hipStream_t stream)
{
    const float* Q    = (const float*)d_in[0];
    const float* K    = (const float*)d_in[1];
    const float* V    = (const float*)d_in[2];
    const int*   mask = (const int*)d_in[3];
    float* out = (float*)d_out;

    // Chunk partials live in d_out (scratch; k3 overwrites all of d_out).
    // Only the compact final KV + ksum (1.07 MB) live in d_ws.
    float* KVp   = out;                                // 64*NC*4096 f32 = 8.4 MB
    float* ksump = KVp + (long)BH * NC * 4096;         // 64*NC*64      = 128 KB
    float* KV    = (float*)d_ws;                       // 64*4096       = 1 MB
    float* ksum  = KV + (long)BH * 4096;               // 64*64         = 16 KB

    hipLaunchKernelGGL(k1_kv, dim3(BH * NC), dim3(256), 0, stream,
                       K, V, mask, KVp, ksump);
    hipLaunchKernelGGL(k2_reduce, dim3(BH), dim3(256), 0, stream,
                       KVp, ksump, KV, ksum);
    hipLaunchKernelGGL(k3_out, dim3(BH * 32), dim3(128), 0, stream,
                       Q, KV, ksum, out);
}